// Round 7
// baseline (146.542 us; speedup 1.0000x reference)
//
#include <hip/hip_runtime.h>
#include <math.h>

#define Bb 8
#define Tt 2048
#define Cc 1024
#define Hh 64
#define BT (Bb * Tt)          // 16384 tokens
#define SLOG2E 0.18033688011112042f   // 0.125 * log2(e)

typedef __attribute__((ext_vector_type(8))) short short8;
typedef __attribute__((ext_vector_type(4))) float floatx4;

__device__ inline unsigned short f2bf(float f) {
  unsigned int u = __builtin_bit_cast(unsigned int, f);
  u += 0x7fff + ((u >> 16) & 1);   // RNE
  return (unsigned short)(u >> 16);
}
__device__ inline float bf2f(unsigned short u) {
  unsigned int x = ((unsigned int)u) << 16;
  return __builtin_bit_cast(float, x);
}

// ---------- Kernel 0: W fp32 [C][H] -> WTf bf16 fragment-major ----------
// B-frag load in qkv = base + lane*8 ushorts: lane-linear, coalesced.
__global__ __launch_bounds__(256) void wconv2(
    const float* __restrict__ Wq, const float* __restrict__ Wk,
    const float* __restrict__ Wv, unsigned short* __restrict__ WTf) {
  int bid = blockIdx.x;
  int w = bid >> 5;            // which W
  int kc = bid & 31;           // 32-k chunk
  const float* __restrict__ W = (w == 0) ? Wq : (w == 1 ? Wk : Wv);
  int t = threadIdx.x;
  int hg = t >> 6, quad = (t >> 4) & 3, lrow = t & 15;
  int g = w * 4 + hg;
  int h = hg * 16 + lrow;
  unsigned short tmp[8];
#pragma unroll
  for (int j = 0; j < 8; ++j)
    tmp[j] = f2bf(W[(size_t)(kc * 32 + quad * 8 + j) * Hh + h]);
  unsigned short* dst = &WTf[((size_t)(g * 32 + kc) * 64 + quad * 16 + lrow) * 8];
  *(ushort4*)dst = make_ushort4(tmp[0], tmp[1], tmp[2], tmp[3]);
  *(ushort4*)(dst + 4) = make_ushort4(tmp[4], tmp[5], tmp[6], tmp[7]);
}

// ---------- Kernel 1: QKV projection, double-buffered (1 barrier/step) ----
// grid 512 (M=32 token rows), 256 threads (4 waves). BK=64, 16 k-steps.
// A staged in alternating 4 KB LDS buffers, rotate-swizzled frag-major
// (conflict-free b128 writes AND reads). B frags lane-linear from WTf.
__global__ __launch_bounds__(256) void qkv6(
    const float* __restrict__ x, const unsigned short* __restrict__ WTf,
    unsigned short* __restrict__ Qb, unsigned short* __restrict__ Kb,
    unsigned short* __restrict__ VTt, int* __restrict__ cnt) {
  __shared__ __align__(16) unsigned short Af[2][2048];

  if (blockIdx.x == 0 && threadIdx.x == 0) *cnt = 0;  // queue for attn5

  int mt = blockIdx.x;
  int t = threadIdx.x;
  int wv = t >> 6, lane = t & 63;
  int lrow = lane & 15, quad = lane >> 4;

  floatx4 acc[2][3];   // [m-sub][n-group]
#pragma unroll
  for (int g2 = 0; g2 < 2; ++g2)
#pragma unroll
    for (int j = 0; j < 3; ++j)
#pragma unroll
      for (int r = 0; r < 4; ++r) acc[g2][j][r] = 0.f;

  // staging coords: thread covers (row srow, 8 k at scg*8)
  int srow = t >> 3, scg = t & 7;
  int skc2 = scg >> 2, squad = scg & 3;
  int sslot = ((srow >> 4) * 2 + skc2) * 64 + squad * 16 +
              (((srow & 15) + squad + 4 * skc2) & 15);
  const float* xp = x + (size_t)(mt * 32 + srow) * Cc + scg * 8;

  // frag-read slots (swizzled)
  int aslot[2][2];
#pragma unroll
  for (int g2 = 0; g2 < 2; ++g2)
#pragma unroll
    for (int kc2 = 0; kc2 < 2; ++kc2)
      aslot[g2][kc2] = ((g2 * 2 + kc2) * 64 + quad * 16 +
                        ((lrow + quad + 4 * kc2) & 15)) * 8;

  const unsigned short* wbase[3];
#pragma unroll
  for (int j = 0; j < 3; ++j)
    wbase[j] = WTf + (size_t)(wv * 3 + j) * 32 * 512 + lane * 8;

  // prologue: stage k-step 0 into buf 0
  {
    float4 v0 = *(const float4*)xp;
    float4 v1 = *(const float4*)(xp + 4);
    short8 a;
    a[0] = (short)f2bf(v0.x); a[1] = (short)f2bf(v0.y);
    a[2] = (short)f2bf(v0.z); a[3] = (short)f2bf(v0.w);
    a[4] = (short)f2bf(v1.x); a[5] = (short)f2bf(v1.y);
    a[6] = (short)f2bf(v1.z); a[7] = (short)f2bf(v1.w);
    *(short8*)&Af[0][sslot * 8] = a;
  }
  __syncthreads();

  for (int kk = 0; kk < 16; ++kk) {
    int cur = kk & 1;
    float4 v0, v1;
    if (kk < 15) {           // issue next step's x load early
      v0 = *(const float4*)(xp + (kk + 1) * 64);
      v1 = *(const float4*)(xp + (kk + 1) * 64 + 4);
    }
    // compute from buf[cur]
    short8 bf[3][2];
    int kg = kk * 2;
#pragma unroll
    for (int j = 0; j < 3; ++j)
#pragma unroll
      for (int kc2 = 0; kc2 < 2; ++kc2)
        bf[j][kc2] = *(const short8*)(wbase[j] + (size_t)(kg + kc2) * 512);
    short8 af[2][2];
#pragma unroll
    for (int g2 = 0; g2 < 2; ++g2)
#pragma unroll
      for (int kc2 = 0; kc2 < 2; ++kc2)
        af[g2][kc2] = *(const short8*)&Af[cur][aslot[g2][kc2]];
#pragma unroll
    for (int g2 = 0; g2 < 2; ++g2)
#pragma unroll
      for (int j = 0; j < 3; ++j) {
        acc[g2][j] = __builtin_amdgcn_mfma_f32_16x16x32_bf16(af[g2][0], bf[j][0], acc[g2][j], 0, 0, 0);
        acc[g2][j] = __builtin_amdgcn_mfma_f32_16x16x32_bf16(af[g2][1], bf[j][1], acc[g2][j], 0, 0, 0);
      }
    if (kk < 15) {           // stage next step into the other buffer
      short8 a;
      a[0] = (short)f2bf(v0.x); a[1] = (short)f2bf(v0.y);
      a[2] = (short)f2bf(v0.z); a[3] = (short)f2bf(v0.w);
      a[4] = (short)f2bf(v1.x); a[5] = (short)f2bf(v1.y);
      a[6] = (short)f2bf(v1.z); a[7] = (short)f2bf(v1.w);
      *(short8*)&Af[1 - cur][sslot * 8] = a;
      __syncthreads();
    }
  }

  // epilogue: D row(m)=quad*4+r, col(n)=lrow
#pragma unroll
  for (int g2 = 0; g2 < 2; ++g2) {
    int tok0 = mt * 32 + g2 * 16 + quad * 4;
#pragma unroll
    for (int j = 0; j < 3; ++j) {
      int nbase = (wv * 3 + j) * 16;
      if (nbase >= 128) {
        int h = nbase - 128 + lrow;
        *(ushort4*)&VTt[(size_t)(tok0 >> 6) * 4096 + h * 64 + (tok0 & 63)] =
            make_ushort4(f2bf(acc[g2][j][0]), f2bf(acc[g2][j][1]),
                         f2bf(acc[g2][j][2]), f2bf(acc[g2][j][3]));
      } else {
        unsigned short* dst = (nbase >= 64) ? Kb : Qb;
        int col = (nbase & 63) + lrow;
#pragma unroll
        for (int r = 0; r < 4; ++r)
          dst[(size_t)(tok0 + r) * Hh + col] = f2bf(acc[g2][j][r]);
      }
    }
  }
}

// ---------- Kernel 2: causal attention, work-queue units ----------
// Work unit = one (b, qt) 32-query tile; 512 units grabbed via atomic
// counter in DESCENDING qt order (big tiles first -> balanced tail).
// 256 threads (4 waves), kt split 4-way across waves, no barriers in the
// K-loop. Unnormalized softmax P = exp2(S*scale*log2e); l via ones-MFMA.
__global__ __launch_bounds__(256) void attn5(
    const unsigned short* __restrict__ Qb, const unsigned short* __restrict__ Kb,
    const unsigned short* __restrict__ VTt, float* __restrict__ out,
    int* __restrict__ cnt) {
  __shared__ __align__(16) unsigned char smem[16384 + 512];
  __shared__ int sU;
  unsigned short* Pall = (unsigned short*)smem;       // 4 waves x 4 KB
  unsigned short* Ocomb = (unsigned short*)smem;      // overlays Pall
  float* Lcomb = (float*)(smem + 16384);              // [4][32]

  int t = threadIdx.x;
  int wv = t >> 6, lane = t & 63;
  int lrow = lane & 15, quad = lane >> 4;
  unsigned short* Pw = Pall + wv * 2048;

  short8 ones;
#pragma unroll
  for (int i = 0; i < 8; ++i) ones[i] = (short)0x3F80;

  for (;;) {
    if (t == 0) sU = atomicAdd(cnt, 1);
    __syncthreads();            // also orders prev unit's reduce vs new P writes
    int u = sU;
    if (u >= 512) break;
    int qt = 63 - (u >> 3);     // descending cost
    int b = u & 7;
    int q0 = qt * 32;
    int nkt = (qt >> 1) + 1;

    short8 aq[2][2];
#pragma unroll
    for (int qs = 0; qs < 2; ++qs)
#pragma unroll
      for (int kc = 0; kc < 2; ++kc)
        aq[qs][kc] = *(const short8*)
            &Qb[(size_t)(b * Tt + q0 + qs * 16 + lrow) * Hh + kc * 32 + quad * 8];

    floatx4 acc_o[2][4];
    floatx4 acc_l[2];
#pragma unroll
    for (int qs = 0; qs < 2; ++qs) {
#pragma unroll
      for (int r = 0; r < 4; ++r) acc_l[qs][r] = 0.f;
#pragma unroll
      for (int hs = 0; hs < 4; ++hs)
#pragma unroll
        for (int r = 0; r < 4; ++r) acc_o[qs][hs][r] = 0.f;
    }

    for (int kt = wv; kt < nkt; kt += 4) {
      int kbase = b * Tt + kt * 64;
      short8 kf[4][2], vf[4][2];
#pragma unroll
      for (int sn = 0; sn < 4; ++sn)
#pragma unroll
        for (int kc = 0; kc < 2; ++kc)
          kf[sn][kc] = *(const short8*)
              &Kb[(size_t)(kbase + sn * 16 + lrow) * Hh + kc * 32 + quad * 8];
      int ktile = b * 32 + kt;
#pragma unroll
      for (int hs = 0; hs < 4; ++hs)
#pragma unroll
        for (int kc = 0; kc < 2; ++kc)
          vf[hs][kc] = *(const short8*)
              &VTt[(size_t)ktile * 4096 + (hs * 16 + lrow) * 64 + kc * 32 + quad * 8];

      floatx4 s[2][4];
#pragma unroll
      for (int qs = 0; qs < 2; ++qs)
#pragma unroll
        for (int sn = 0; sn < 4; ++sn) {
          floatx4 z;
#pragma unroll
          for (int r = 0; r < 4; ++r) z[r] = 0.f;
          z = __builtin_amdgcn_mfma_f32_16x16x32_bf16(aq[qs][0], kf[sn][0], z, 0, 0, 0);
          z = __builtin_amdgcn_mfma_f32_16x16x32_bf16(aq[qs][1], kf[sn][1], z, 0, 0, 0);
          s[qs][sn] = z;
        }

      bool diag = (kt == nkt - 1);
#pragma unroll
      for (int qs = 0; qs < 2; ++qs)
#pragma unroll
        for (int sn = 0; sn < 4; ++sn) {
          int k5 = (sn & 1) * 16 + lrow;
          int slot = qs * 2 + (sn >> 1);
          int rlbase = (k5 >> 3) * 16;
#pragma unroll
          for (int r = 0; r < 4; ++r) {
            float v = s[qs][sn][r] * SLOG2E;
            if (diag) {
              int gk = kt * 64 + sn * 16 + lrow;
              int gq = q0 + qs * 16 + quad * 4 + r;
              if (gk > gq) v = -INFINITY;
            }
            float p = exp2f(v);
            Pw[slot * 512 + (rlbase + quad * 4 + r) * 8 + (k5 & 7)] = f2bf(p);
          }
        }

      short8 ap[2][2];
#pragma unroll
      for (int qs = 0; qs < 2; ++qs)
#pragma unroll
        for (int kc = 0; kc < 2; ++kc)
          ap[qs][kc] = *(const short8*)&Pw[(qs * 2 + kc) * 512 + lane * 8];

#pragma unroll
      for (int qs = 0; qs < 2; ++qs) {
        acc_l[qs] = __builtin_amdgcn_mfma_f32_16x16x32_bf16(ap[qs][0], ones, acc_l[qs], 0, 0, 0);
        acc_l[qs] = __builtin_amdgcn_mfma_f32_16x16x32_bf16(ap[qs][1], ones, acc_l[qs], 0, 0, 0);
#pragma unroll
        for (int hs = 0; hs < 4; ++hs) {
          acc_o[qs][hs] = __builtin_amdgcn_mfma_f32_16x16x32_bf16(ap[qs][0], vf[hs][0], acc_o[qs][hs], 0, 0, 0);
          acc_o[qs][hs] = __builtin_amdgcn_mfma_f32_16x16x32_bf16(ap[qs][1], vf[hs][1], acc_o[qs][hs], 0, 0, 0);
        }
      }
    }

    // ---- combine 4 wave-partials ----
#pragma unroll
    for (int qs = 0; qs < 2; ++qs)
#pragma unroll
      for (int hs = 0; hs < 4; ++hs) {
        int s8 = qs * 4 + hs;
        *(ushort4*)&Ocomb[((wv * 8 + s8) * 64 + lane) * 4] =
            make_ushort4(f2bf(acc_o[qs][hs][0]), f2bf(acc_o[qs][hs][1]),
                         f2bf(acc_o[qs][hs][2]), f2bf(acc_o[qs][hs][3]));
      }
    if (lrow == 0) {
#pragma unroll
      for (int qs = 0; qs < 2; ++qs)
#pragma unroll
        for (int r = 0; r < 4; ++r)
          Lcomb[wv * 32 + qs * 16 + quad * 4 + r] = acc_l[qs][r];
    }
    __syncthreads();

#pragma unroll
    for (int s2 = 0; s2 < 2; ++s2) {
      int slot = wv * 2 + s2;         // 0..7
      int qsub = slot >> 2, hs = slot & 3;
      float o[4] = {0.f, 0.f, 0.f, 0.f};
#pragma unroll
      for (int w = 0; w < 4; ++w) {
        ushort4 pk = *(const ushort4*)&Ocomb[((w * 8 + slot) * 64 + lane) * 4];
        o[0] += bf2f(pk.x); o[1] += bf2f(pk.y);
        o[2] += bf2f(pk.z); o[3] += bf2f(pk.w);
      }
#pragma unroll
      for (int r = 0; r < 4; ++r) {
        float lv = 0.f;
#pragma unroll
        for (int w = 0; w < 4; ++w)
          lv += Lcomb[w * 32 + qsub * 16 + quad * 4 + r];
        int row = q0 + qsub * 16 + quad * 4 + r;
        out[(size_t)(b * Tt + row) * Hh + hs * 16 + lrow] = o[r] / lv;
      }
    }
    // next-iteration grab barrier orders reduce-reads vs next P-writes
  }
}

extern "C" void kernel_launch(void* const* d_in, const int* in_sizes, int n_in,
                              void* d_out, int out_size, void* d_ws, size_t ws_size,
                              hipStream_t stream) {
  const float* x = (const float*)d_in[0];
  const float* Wq = (const float*)d_in[1];
  const float* Wk = (const float*)d_in[2];
  const float* Wv = (const float*)d_in[3];
  float* out = (float*)d_out;

  unsigned short* WTf = (unsigned short*)d_ws;         // 192*1024 frag-major
  unsigned short* Qb = WTf + 192 * 1024;               // [BT][64]
  unsigned short* Kb = Qb + (size_t)BT * Hh;           // [BT][64]
  unsigned short* VTt = Kb + (size_t)BT * Hh;          // [BT/64][64][64]
  int* cnt = (int*)(VTt + (size_t)BT * Hh);            // work-queue counter

  wconv2<<<dim3(96), dim3(256), 0, stream>>>(Wq, Wk, Wv, WTf);
  qkv6<<<dim3(512), dim3(256), 0, stream>>>(x, WTf, Qb, Kb, VTt, cnt);
  attn5<<<dim3(1024), dim3(256), 0, stream>>>(Qb, Kb, VTt, out, cnt);
}

// Round 8
// 132.388 us; speedup vs baseline: 1.1069x; 1.1069x over previous
//
#include <hip/hip_runtime.h>
#include <math.h>

#define Bb 8
#define Tt 2048
#define Cc 1024
#define Hh 64
#define BT (Bb * Tt)          // 16384 tokens
#define SLOG2E 0.18033688011112042f   // 0.125 * log2(e)

typedef __attribute__((ext_vector_type(8))) short short8;
typedef __attribute__((ext_vector_type(4))) float floatx4;

__device__ inline unsigned short f2bf(float f) {
  unsigned int u = __builtin_bit_cast(unsigned int, f);
  u += 0x7fff + ((u >> 16) & 1);   // RNE
  return (unsigned short)(u >> 16);
}
__device__ inline float bf2f(unsigned short u) {
  unsigned int x = ((unsigned int)u) << 16;
  return __builtin_bit_cast(float, x);
}

// Fragment-major layouts (all bf16):
//  Ff tile (Qf, Kf): per 16-token tile, [tile16][kc][lane][8]:
//    lane l holds token = tile16*16 + (l&15), h = kc*32 + (l>>4)*8 + j.
//    Works as BOTH MFMA A-frag (m=token,k=h) and B-frag (n=token,k=h):
//    load = base + lane*16B, coalesced single-burst.
//  Vf: per 32-token tile, [tile32][hs][lane][8]:
//    lane l holds h = hs*16 + (l&15), token = tile32*32 + (l>>4)*8 + j.

// ---------- Kernel 0: W fp32 [C][H] -> WTf bf16 fragment-major ----------
__global__ __launch_bounds__(256) void wconv2(
    const float* __restrict__ Wq, const float* __restrict__ Wk,
    const float* __restrict__ Wv, unsigned short* __restrict__ WTf) {
  int bid = blockIdx.x;
  int w = bid >> 5;            // which W
  int kc = bid & 31;           // 32-k chunk
  const float* __restrict__ W = (w == 0) ? Wq : (w == 1 ? Wk : Wv);
  int t = threadIdx.x;
  int hg = t >> 6, quad = (t >> 4) & 3, lrow = t & 15;
  int g = w * 4 + hg;
  int h = hg * 16 + lrow;
  unsigned short tmp[8];
#pragma unroll
  for (int j = 0; j < 8; ++j)
    tmp[j] = f2bf(W[(size_t)(kc * 32 + quad * 8 + j) * Hh + h]);
  unsigned short* dst = &WTf[((size_t)(g * 32 + kc) * 64 + quad * 16 + lrow) * 8];
  *(ushort4*)dst = make_ushort4(tmp[0], tmp[1], tmp[2], tmp[3]);
  *(ushort4*)(dst + 4) = make_ushort4(tmp[4], tmp[5], tmp[6], tmp[7]);
}

// ---------- Kernel 1: QKV projection, double-buffered, frag-major outputs --
// grid 512 (M=32 tokens), 256 threads (4 waves). BK=64, 16 k-steps.
// Epilogue: D-tiles -> LDS (32x192, stride 208) -> coalesced frag-major
// b128 stores of Qf/Kf/Vf.
__global__ __launch_bounds__(256) void qkv7(
    const float* __restrict__ x, const unsigned short* __restrict__ WTf,
    unsigned short* __restrict__ Qf, unsigned short* __restrict__ Kf,
    unsigned short* __restrict__ Vf) {
  __shared__ __align__(16) unsigned short smem7[6656];  // dbuf 2x2048 | Dtile 32x208

  int mt = blockIdx.x;
  int t = threadIdx.x;
  int wv = t >> 6, lane = t & 63;
  int lrow = lane & 15, quad = lane >> 4;

  floatx4 acc[2][3];   // [m-sub][n-group]
#pragma unroll
  for (int g2 = 0; g2 < 2; ++g2)
#pragma unroll
    for (int j = 0; j < 3; ++j)
#pragma unroll
      for (int r = 0; r < 4; ++r) acc[g2][j][r] = 0.f;

  // staging coords: thread covers (row srow, 8 k at scg*8)
  int srow = t >> 3, scg = t & 7;
  int skc2 = scg >> 2, squad = scg & 3;
  int sslot = ((srow >> 4) * 2 + skc2) * 64 + squad * 16 +
              (((srow & 15) + squad + 4 * skc2) & 15);
  const float* xp = x + (size_t)(mt * 32 + srow) * Cc + scg * 8;

  // frag-read slots (rotate swizzle, conflict-free b128 write+read)
  int aslot[2][2];
#pragma unroll
  for (int g2 = 0; g2 < 2; ++g2)
#pragma unroll
    for (int kc2 = 0; kc2 < 2; ++kc2)
      aslot[g2][kc2] = ((g2 * 2 + kc2) * 64 + quad * 16 +
                        ((lrow + quad + 4 * kc2) & 15)) * 8;

  const unsigned short* wbase[3];
#pragma unroll
  for (int j = 0; j < 3; ++j)
    wbase[j] = WTf + (size_t)(wv * 3 + j) * 32 * 512 + lane * 8;

  // prologue: stage k-step 0 into buf 0
  {
    float4 v0 = *(const float4*)xp;
    float4 v1 = *(const float4*)(xp + 4);
    short8 a;
    a[0] = (short)f2bf(v0.x); a[1] = (short)f2bf(v0.y);
    a[2] = (short)f2bf(v0.z); a[3] = (short)f2bf(v0.w);
    a[4] = (short)f2bf(v1.x); a[5] = (short)f2bf(v1.y);
    a[6] = (short)f2bf(v1.z); a[7] = (short)f2bf(v1.w);
    *(short8*)&smem7[sslot * 8] = a;
  }
  __syncthreads();

  for (int kk = 0; kk < 16; ++kk) {
    int cur = kk & 1;
    float4 v0, v1;
    if (kk < 15) {
      v0 = *(const float4*)(xp + (kk + 1) * 64);
      v1 = *(const float4*)(xp + (kk + 1) * 64 + 4);
    }
    short8 bf[3][2];
    int kg = kk * 2;
#pragma unroll
    for (int j = 0; j < 3; ++j)
#pragma unroll
      for (int kc2 = 0; kc2 < 2; ++kc2)
        bf[j][kc2] = *(const short8*)(wbase[j] + (size_t)(kg + kc2) * 512);
    short8 af[2][2];
#pragma unroll
    for (int g2 = 0; g2 < 2; ++g2)
#pragma unroll
      for (int kc2 = 0; kc2 < 2; ++kc2)
        af[g2][kc2] = *(const short8*)&smem7[cur * 2048 + aslot[g2][kc2]];
#pragma unroll
    for (int g2 = 0; g2 < 2; ++g2)
#pragma unroll
      for (int j = 0; j < 3; ++j) {
        acc[g2][j] = __builtin_amdgcn_mfma_f32_16x16x32_bf16(af[g2][0], bf[j][0], acc[g2][j], 0, 0, 0);
        acc[g2][j] = __builtin_amdgcn_mfma_f32_16x16x32_bf16(af[g2][1], bf[j][1], acc[g2][j], 0, 0, 0);
      }
    if (kk < 15) {
      short8 a;
      a[0] = (short)f2bf(v0.x); a[1] = (short)f2bf(v0.y);
      a[2] = (short)f2bf(v0.z); a[3] = (short)f2bf(v0.w);
      a[4] = (short)f2bf(v1.x); a[5] = (short)f2bf(v1.y);
      a[6] = (short)f2bf(v1.z); a[7] = (short)f2bf(v1.w);
      *(short8*)&smem7[(1 - cur) * 2048 + sslot * 8] = a;
      __syncthreads();
    }
  }

  // ---- epilogue: D-tiles -> LDS -> frag-major global ----
  __syncthreads();   // last MFMA LDS reads done before overwrite
#pragma unroll
  for (int g2 = 0; g2 < 2; ++g2)
#pragma unroll
    for (int j = 0; j < 3; ++j) {
      int col = (wv * 3 + j) * 16 + lrow;
#pragma unroll
      for (int r = 0; r < 4; ++r)
        smem7[(g2 * 16 + quad * 4 + r) * 208 + col] = f2bf(acc[g2][j][r]);
    }
  __syncthreads();
#pragma unroll
  for (int fi = 0; fi < 3; ++fi) {
    int idx = fi * 256 + t;
    if (idx < 512) {
      // Q (idx<256) / K frag tiles: (g2, kc, lane)
      int which = idx >> 8;
      int sub = idx & 255;
      int g2k = sub >> 6, lane_s = sub & 63;
      int g2_ = g2k >> 1, kc_ = g2k & 1;
      int tokrow = g2_ * 16 + (lane_s & 15);
      int hbase = which * 64 + kc_ * 32 + (lane_s >> 4) * 8;
      short8 v = *(const short8*)&smem7[tokrow * 208 + hbase];
      unsigned short* dstf = which ? Kf : Qf;
      *(short8*)&dstf[((size_t)(mt * 2 + g2_) * 2 + kc_) * 512 + lane_s * 8] = v;
    } else {
      // V frag tile: (hs, lane)
      int sub = idx - 512;
      int hs = sub >> 6, lane_s = sub & 63;
      int hcol = 128 + hs * 16 + (lane_s & 15);
      int tok0 = (lane_s >> 4) * 8;
      unsigned short tmp[8];
#pragma unroll
      for (int jj = 0; jj < 8; ++jj) tmp[jj] = smem7[(tok0 + jj) * 208 + hcol];
      unsigned short* dv = &Vf[((size_t)(mt * 4 + hs)) * 512 + lane_s * 8];
      *(ushort4*)dv = make_ushort4(tmp[0], tmp[1], tmp[2], tmp[3]);
      *(ushort4*)(dv + 4) = make_ushort4(tmp[4], tmp[5], tmp[6], tmp[7]);
    }
  }
}

// ---------- Kernel 2: causal attention, frag-major single-burst loads ------
// grid 256 blocks (b, j), 512 threads (8 waves). Block handles query tiles
// j and 63-j sequentially; key tiles split 8-way across waves; no barriers
// in K-loop. Unnormalized softmax P = exp2(S*scale*log2e); l via ones-MFMA.
__global__ __launch_bounds__(512) void attn6(
    const unsigned short* __restrict__ Qf, const unsigned short* __restrict__ Kf,
    const unsigned short* __restrict__ Vf, float* __restrict__ out) {
  __shared__ __align__(16) unsigned char smem[33 * 1024];
  unsigned short* Pall = (unsigned short*)smem;
  unsigned short* Ocomb = (unsigned short*)smem;
  float* Lcomb = (float*)(smem + 32768);

  int bid = blockIdx.x;
  int b = bid >> 5;
  int j = bid & 31;
  int t = threadIdx.x;
  int wv = t >> 6, lane = t & 63;
  int lrow = lane & 15, quad = lane >> 4;

  unsigned short* Pw = Pall + wv * 2048;

  short8 ones;
#pragma unroll
  for (int i = 0; i < 8; ++i) ones[i] = (short)0x3F80;

  for (int half = 0; half < 2; ++half) {
    int qt = half ? (63 - j) : j;
    int q0 = qt * 32;
    int nkt = (qt >> 1) + 1;
    int qtile16 = b * 128 + qt * 2;

    short8 aq[2][2];
#pragma unroll
    for (int qs = 0; qs < 2; ++qs)
#pragma unroll
      for (int kc = 0; kc < 2; ++kc)
        aq[qs][kc] = *(const short8*)
            &Qf[((size_t)(qtile16 + qs) * 2 + kc) * 512 + lane * 8];

    floatx4 acc_o[2][4];
    floatx4 acc_l[2];
#pragma unroll
    for (int qs = 0; qs < 2; ++qs) {
#pragma unroll
      for (int r = 0; r < 4; ++r) acc_l[qs][r] = 0.f;
#pragma unroll
      for (int hs = 0; hs < 4; ++hs)
#pragma unroll
        for (int r = 0; r < 4; ++r) acc_o[qs][hs][r] = 0.f;
    }

    for (int kt = wv; kt < nkt; kt += 8) {
      int ktile16 = b * 128 + kt * 4;
      int ktile32 = b * 64 + kt * 2;
      short8 kf[4][2], vf[4][2];
#pragma unroll
      for (int sn = 0; sn < 4; ++sn)
#pragma unroll
        for (int kc = 0; kc < 2; ++kc)
          kf[sn][kc] = *(const short8*)
              &Kf[((size_t)(ktile16 + sn) * 2 + kc) * 512 + lane * 8];
#pragma unroll
      for (int hs = 0; hs < 4; ++hs)
#pragma unroll
        for (int kc = 0; kc < 2; ++kc)
          vf[hs][kc] = *(const short8*)
              &Vf[((size_t)(ktile32 + kc) * 4 + hs) * 512 + lane * 8];

      floatx4 s[2][4];
#pragma unroll
      for (int qs = 0; qs < 2; ++qs)
#pragma unroll
        for (int sn = 0; sn < 4; ++sn) {
          floatx4 z;
#pragma unroll
          for (int r = 0; r < 4; ++r) z[r] = 0.f;
          z = __builtin_amdgcn_mfma_f32_16x16x32_bf16(aq[qs][0], kf[sn][0], z, 0, 0, 0);
          z = __builtin_amdgcn_mfma_f32_16x16x32_bf16(aq[qs][1], kf[sn][1], z, 0, 0, 0);
          s[qs][sn] = z;
        }

      bool diag = (kt == nkt - 1);
#pragma unroll
      for (int qs = 0; qs < 2; ++qs)
#pragma unroll
        for (int sn = 0; sn < 4; ++sn) {
          int k5 = (sn & 1) * 16 + lrow;
          int slot = qs * 2 + (sn >> 1);
          int rlbase = (k5 >> 3) * 16;
#pragma unroll
          for (int r = 0; r < 4; ++r) {
            float v = s[qs][sn][r] * SLOG2E;
            if (diag) {
              int gk = kt * 64 + sn * 16 + lrow;
              int gq = q0 + qs * 16 + quad * 4 + r;
              if (gk > gq) v = -INFINITY;
            }
            float p = exp2f(v);
            Pw[slot * 512 + (rlbase + quad * 4 + r) * 8 + (k5 & 7)] = f2bf(p);
          }
        }

      short8 ap[2][2];
#pragma unroll
      for (int qs = 0; qs < 2; ++qs)
#pragma unroll
        for (int kc = 0; kc < 2; ++kc)
          ap[qs][kc] = *(const short8*)&Pw[(qs * 2 + kc) * 512 + lane * 8];

#pragma unroll
      for (int qs = 0; qs < 2; ++qs) {
        acc_l[qs] = __builtin_amdgcn_mfma_f32_16x16x32_bf16(ap[qs][0], ones, acc_l[qs], 0, 0, 0);
        acc_l[qs] = __builtin_amdgcn_mfma_f32_16x16x32_bf16(ap[qs][1], ones, acc_l[qs], 0, 0, 0);
#pragma unroll
        for (int hs = 0; hs < 4; ++hs) {
          acc_o[qs][hs] = __builtin_amdgcn_mfma_f32_16x16x32_bf16(ap[qs][0], vf[hs][0], acc_o[qs][hs], 0, 0, 0);
          acc_o[qs][hs] = __builtin_amdgcn_mfma_f32_16x16x32_bf16(ap[qs][1], vf[hs][1], acc_o[qs][hs], 0, 0, 0);
        }
      }
    }

    // ---- combine 8 wave-partials ----
#pragma unroll
    for (int qs = 0; qs < 2; ++qs)
#pragma unroll
      for (int hs = 0; hs < 4; ++hs) {
        int s8 = qs * 4 + hs;
        *(ushort4*)&Ocomb[((wv * 8 + s8) * 64 + lane) * 4] =
            make_ushort4(f2bf(acc_o[qs][hs][0]), f2bf(acc_o[qs][hs][1]),
                         f2bf(acc_o[qs][hs][2]), f2bf(acc_o[qs][hs][3]));
      }
    if (lrow == 0) {
#pragma unroll
      for (int qs = 0; qs < 2; ++qs)
#pragma unroll
        for (int r = 0; r < 4; ++r)
          Lcomb[wv * 32 + qs * 16 + quad * 4 + r] = acc_l[qs][r];
    }
    __syncthreads();

    {
      int qsub = wv >> 2, hs = wv & 3;
      float o[4] = {0.f, 0.f, 0.f, 0.f};
#pragma unroll
      for (int w = 0; w < 8; ++w) {
        ushort4 pk = *(const ushort4*)&Ocomb[((w * 8 + wv) * 64 + lane) * 4];
        o[0] += bf2f(pk.x); o[1] += bf2f(pk.y);
        o[2] += bf2f(pk.z); o[3] += bf2f(pk.w);
      }
#pragma unroll
      for (int r = 0; r < 4; ++r) {
        float lv = 0.f;
#pragma unroll
        for (int w = 0; w < 8; ++w)
          lv += Lcomb[w * 32 + qsub * 16 + quad * 4 + r];
        int row = q0 + qsub * 16 + quad * 4 + r;
        out[(size_t)(b * Tt + row) * Hh + hs * 16 + lrow] = o[r] / lv;
      }
    }
    __syncthreads();
  }
}

extern "C" void kernel_launch(void* const* d_in, const int* in_sizes, int n_in,
                              void* d_out, int out_size, void* d_ws, size_t ws_size,
                              hipStream_t stream) {
  const float* x = (const float*)d_in[0];
  const float* Wq = (const float*)d_in[1];
  const float* Wk = (const float*)d_in[2];
  const float* Wv = (const float*)d_in[3];
  float* out = (float*)d_out;

  unsigned short* WTf = (unsigned short*)d_ws;            // 192*1024
  unsigned short* Qf = WTf + 192 * 1024;                  // (BT/16)*2*512
  unsigned short* Kf = Qf + (size_t)(BT / 16) * 2 * 512;  // (BT/16)*2*512
  unsigned short* Vf = Kf + (size_t)(BT / 16) * 2 * 512;  // (BT/32)*4*512

  wconv2<<<dim3(96), dim3(256), 0, stream>>>(Wq, Wk, Wv, WTf);
  qkv7<<<dim3(512), dim3(256), 0, stream>>>(x, WTf, Qf, Kf, Vf);
  attn6<<<dim3(256), dim3(512), 0, stream>>>(Qf, Kf, Vf, out);
}